// Round 1
// baseline (64.616 us; speedup 1.0000x reference)
//
#include <hip/hip_runtime.h>
#include <stdint.h>

// Find_Ring_Atoms: B independent sequential graph algorithms.
// One wave (64 lanes) per batch element:
//   - lane l holds Tree[l], ring_idx[l][0/1], edge[b][l][0..3]+1 (registers)
//   - lnf/nnv/vb0/vb1/vb0b are 51-bit wave-uniform uint64 bitmasks (SALU)
//   - Tree[x] lookups via v_readlane (uniform index) -> short dependency chain
constexpr int BATCH = 16384;
constexpr int A     = 50;
constexpr int NN    = 51;   // A + 1
constexpr int DD    = 4;
constexpr int MAXR  = 16;
constexpr int WPB   = 4;    // waves per block (block = 256 threads)

__global__ __launch_bounds__(WPB * 64)
void find_ring_atoms_kernel(const int* __restrict__ edge, int* __restrict__ out)
{
    const int lane = threadIdx.x & 63;
    const int wid  = threadIdx.x >> 6;
    const int b    = blockIdx.x * WPB + wid;
    if (b >= BATCH) return;

    int* out_tree  = out + (size_t)b * NN;                                  // (B,51)
    int* out_ridx  = out + (size_t)BATCH * NN + (size_t)b * (NN * 2);       // (B,51,2)
    int* out_rings = out + (size_t)BATCH * NN * 3 + (size_t)b * (MAXR * A); // (B,16,50)

    // ---- preload this element's edge table: lane l holds me[b][l+1][0..3] ----
    int e0 = 0, e1 = 0, e2 = 0, e3 = 0;
    if (lane < A) {
        const int4 ev = *reinterpret_cast<const int4*>(edge + ((size_t)b * A + lane) * DD);
        e0 = ev.x + 1; e1 = ev.y + 1; e2 = ev.z + 1; e3 = ev.w + 1;  // me = edge+1, -1 -> 0
    }

    // lnf: 1 = not yet found. bits 0 and 1 start cleared.
    uint64_t L = (((uint64_t)1 << NN) - 1) & ~(uint64_t)3;
    // nnv: 1 = not yet visited. bit 0 starts cleared.
    uint64_t V = (((uint64_t)1 << NN) - 1) & ~(uint64_t)1;

    int tree  = 0;            // lane l: Tree[l]
    int ring0 = 0, ring1 = 0; // lane l: ring_idx[l][0], ring_idx[l][1]
    int num_rings = 0;        // wave-uniform
    int visiting  = 1;        // first visit is node 1

    // ---- tree construction: 50 visits max ----
    for (int it = 0; it < A; ++it) {
        const int vm1 = visiting - 1;  // visiting >= 1 always here
        const int n0 = __builtin_amdgcn_readlane(e0, vm1);
        const int n1 = __builtin_amdgcn_readlane(e1, vm1);
        const int n2 = __builtin_amdgcn_readlane(e2, vm1);
        const int n3 = __builtin_amdgcn_readlane(e3, vm1);
        #pragma unroll
        for (int d = 0; d < DD; ++d) {
            const int nxt = (d == 0) ? n0 : (d == 1) ? n1 : (d == 2) ? n2 : n3;
            const uint64_t bit = (uint64_t)1 << nxt;
            const bool slnf = (L & bit) != 0;   // not yet found
            const bool slnv = (V & bit) != 0;   // not yet visited
            const bool cyc  = (!slnf) && slnv && (nxt != 0);
            if (cyc) {
                // ring_idx.at[b, num_rings, :].add — dropped if num_rings >= 51
                if (num_rings < NN && lane == num_rings) { ring0 += visiting; ring1 += nxt; }
                num_rings++;
            }
            if (slnf && lane == nxt) tree = visiting;  // Tree[nxt] += slnf*visiting (set-once)
            L &= ~bit;                                  // lnf[nxt] = 0
        }
        V &= ~((uint64_t)1 << visiting);                // nnv[visiting] = 0
        const uint64_t M = V & ~L;  // found & not visited
        if (M == 0) break;          // argmax -> 0 -> all remaining visits are no-ops
        visiting = (int)__builtin_ctzll(M);             // argmax = first set index
    }

    // ---- ring reconstruction ----
    const int nr_eff = (num_rings < MAXR) ? num_rings : MAXR;  // rows >= 16 are dropped scatters
    for (int i = 0; i < MAXR; ++i) {
        int rowval = 0;  // lane s: rings[b][i][s] (0 -> outputs -1)
        if (i < nr_eff) {
            const int s0 = __builtin_amdgcn_readlane(ring0, i);
            const int s1 = __builtin_amdgcn_readlane(ring1, i);

            // mark0: vb0 = chain(s0). Chain reaches 0 in <= 50 steps; start==0 => no-op tail.
            uint64_t vb0 = (uint64_t)1 << s0;
            int cur = s0;
            for (int k = 0; k < A && cur != 0; ++k) {
                const int nxt = __builtin_amdgcn_readlane(tree, cur);
                vb0 |= (uint64_t)1 << nxt;
                cur = nxt;
            }

            // b1: walk from s1, emit until path meets vb0 (same), keep filling vb1.
            uint64_t vb1 = (uint64_t)1 << s1;
            int air = 0;
            if (lane == 0) rowval = s1;          // rings[b,i,0] = s1
            cur = s1;
            for (int k = 0; k < A && cur != 0; ++k) {
                const int nxt = __builtin_amdgcn_readlane(tree, cur);
                const bool same = (vb0 & vb1) != 0;   // checked BEFORE adding nxt to vb1
                if (!same) {
                    air += 1;
                    if (air < A && lane == air) rowval += nxt;  // air>=50: dropped
                }
                vb1 |= (uint64_t)1 << nxt;
                cur = nxt;
            }

            // b2 prologue
            uint64_t vb0b = (uint64_t)1 << s0;
            air += 1;
            if (air < A && lane == air) rowval = s0;  // rings[b,i,air] = s0 (fresh slot)
            cur = s0;
            for (int k = 0; k < A && cur != 0; ++k) {
                const int nxt = __builtin_amdgcn_readlane(tree, cur);
                vb0b |= (uint64_t)1 << nxt;           // updated BEFORE same (b2 order!)
                const bool same = (vb0b & vb1) != 0;
                if (!same) {
                    air += 1;
                    if (air < A && lane == air) rowval += nxt;
                }
                cur = nxt;
            }
        }
        if (lane < A) out_rings[i * A + lane] = rowval - 1;  // rings - 1; untouched = -1
    }

    // ---- Tree and ring_idx outputs ----
    if (lane < NN) {
        out_tree[lane] = tree;
        reinterpret_cast<int2*>(out_ridx)[lane] = make_int2(ring0, ring1);
    }
}

extern "C" void kernel_launch(void* const* d_in, const int* in_sizes, int n_in,
                              void* d_out, int out_size, void* d_ws, size_t ws_size,
                              hipStream_t stream) {
    const int* edge = (const int*)d_in[0];
    int* out = (int*)d_out;
    dim3 grid(BATCH / WPB);
    dim3 block(WPB * 64);
    hipLaunchKernelGGL(find_ring_atoms_kernel, grid, block, 0, stream, edge, out);
}